// Round 10
// baseline (482.918 us; speedup 1.0000x reference)
//
#include <hip/hip_runtime.h>

#define N_NODES 50000
#define N_EDGES 1600000
#define CAP 64            // bucket capacity per node; Poisson(32) tail @64 ~ 1e-7
#define OVF_CAP 8192

// Workspace element offsets (4-byte units). Peak ~71 MB.
#define O_CNTO   0         // int[50000]  out-degree
#define O_CNTI   50000     // int[50000]  in-degree (also bucket fill)
#define O_OVFN   100000    // int[1]      overflow count
#define O_OVF    100002    // int2[8192]  overflow (dst,src) pairs
#define O_BUCKET 120000    // int[50000*64] src per slot
#define O_HB     3320000   // uint[3.2M]  bf16x2 h*norm_out
#define O_AGGB   6520000   // uint[3.2M]  bf16x2 agg rows (256 B/node)
#define O_WT     9720000   // uint[24576] bf16 W^T for Q,K,V: [3][128 n][64 k-pairs]
#define O_QB     9750000   // uint[3.2M]  bf16x2 Q rows (64 uints/node)
#define O_KF     12950000  // uint[1.6M]  fp8 e4m3 K rows (128 B/node)
#define O_VB     14550000  // uint[3.2M]  bf16x2 V rows (256 B/node)

typedef unsigned int uint;
typedef unsigned short ushort;
typedef __attribute__((ext_vector_type(8))) short short8;
typedef __attribute__((ext_vector_type(4))) float floatx4;

union U16 { uint4 u; short8 s; };

__device__ __forceinline__ uint f2bf2(float a, float b) {
    uint ua = __float_as_uint(a); ua = (ua + 0x7fffu + ((ua >> 16) & 1u)) >> 16;
    uint ub = __float_as_uint(b); ub = (ub + 0x7fffu + ((ub >> 16) & 1u)) >> 16;
    return ua | (ub << 16);
}
__device__ __forceinline__ float bflo(uint u) { return __uint_as_float(u << 16); }
__device__ __forceinline__ float bfhi(uint u) { return __uint_as_float(u & 0xffff0000u); }

// f >= 0 (post-relu) -> e4m3fn byte, RNE, clamp 448
__device__ __forceinline__ uint f2e4m3(float f) {
    f = fminf(f, 448.f);
    if (f < 0.015625f) return (uint)(f * 512.f + 0.5f);   // subnormal (incl. 0)
    uint x = __float_as_uint(f);
    x += 0x7FFFFu + ((x >> 20) & 1u);                     // RNE at bit 20
    uint b = (((x >> 23) - 120u) << 3) | ((x >> 20) & 7u);
    return min(b, 0x7Eu);
}
// e4m3fn byte (sign=0) -> float
__device__ __forceinline__ float e4m3f(uint b) {
    float fn = __uint_as_float(0x3C000000u + (b << 20));  // normal (b>=8)
    float fs = (float)b * (1.f / 512.f);                  // subnormal
    return (b >= 8u) ? fn : fs;
}

// One-pass build: out-degree histogram + dst-buckets (with overflow safety net).
__global__ __launch_bounds__(256) void k_build(const int* __restrict__ src,
                                               const int* __restrict__ dst,
                                               int* cnt_out, int* cnt_in,
                                               int* __restrict__ bucket,
                                               int* ovf_n, int2* __restrict__ ovf) {
    int e = blockIdx.x * 256 + threadIdx.x;
    if (e < N_EDGES) {
        int s = src[e], d = dst[e];
        atomicAdd(&cnt_out[s], 1);
        int pos = atomicAdd(&cnt_in[d], 1);
        if (pos < CAP) {
            bucket[(d << 6) + pos] = s;
        } else {
            int o = atomicAdd(ovf_n, 1);
            if (o < OVF_CAP) ovf[o] = make_int2(d, s);
        }
    }
}

// Fused: blocks [0,96) cast W^T to bf16; blocks [96,..) compute hb.
__global__ __launch_bounds__(256) void k_hbwt(
    const float* __restrict__ h, const int* __restrict__ cnt_out,
    uint* __restrict__ hb,
    const float* __restrict__ WQ, const float* __restrict__ WK,
    const float* __restrict__ WV, uint* __restrict__ wt)
{
    if (blockIdx.x < 96) {
        int idx = blockIdx.x * 256 + threadIdx.x;   // [0, 3*8192)
        int y = idx >> 13;
        int rem = idx & 8191;
        int k2 = rem >> 7;          // 0..63
        int n  = rem & 127;         // coalesced reads
        const float* W = (y == 0) ? WQ : (y == 1) ? WK : WV;
        float a = W[(2 * k2) * 128 + n];
        float b = W[(2 * k2 + 1) * 128 + n];
        wt[(y << 13) + (n << 6) + k2] = f2bf2(a, b);
    } else {
        int idx = (blockIdx.x - 96) * 256 + threadIdx.x;   // [0, N*64)
        int n = idx >> 6;
        float no = rsqrtf(fmaxf((float)cnt_out[n], 1.0f));
        float2 hv = *(const float2*)(h + ((size_t)idx << 1));
        hb[idx] = f2bf2(hv.x * no, hv.y * no);
    }
}

// aggb[n] = bf16( rsqrt(max(deg_in,1)) * sum_{slots of n} hb[s] ); unroll x8
__global__ __launch_bounds__(256) void k_agg(
    const int* __restrict__ cnt_in, const int* __restrict__ bucket,
    const int* __restrict__ ovf_n, const int2* __restrict__ ovf,
    const uint* __restrict__ hb, uint* __restrict__ aggb)
{
    int n = blockIdx.x * 4 + (threadIdx.x >> 6);
    int lane = threadIdx.x & 63;
    int cnt = cnt_in[n];
    int m = min(cnt, CAP);
    const int* b = bucket + ((size_t)n << 6);
    float ax = 0.f, ay = 0.f;
    int i = 0;
    for (; i + 8 <= m; i += 8) {
        int s[8]; uint u[8];
        #pragma unroll
        for (int j = 0; j < 8; ++j) s[j] = b[i + j];
        #pragma unroll
        for (int j = 0; j < 8; ++j) u[j] = hb[((size_t)s[j] << 6) + lane];
        #pragma unroll
        for (int j = 0; j < 8; ++j) { ax += bflo(u[j]); ay += bfhi(u[j]); }
    }
    for (; i < m; ++i) {
        int s = b[i];
        uint u = hb[((size_t)s << 6) + lane];
        ax += bflo(u);
        ay += bfhi(u);
    }
    if (cnt > CAP) {                       // statistically never; correctness net
        int on = min(*ovf_n, OVF_CAP);
        for (int j = 0; j < on; ++j) {
            int2 p = ovf[j];
            if (p.x == n) {
                uint u = hb[((size_t)p.y << 6) + lane];
                ax += bflo(u);
                ay += bfhi(u);
            }
        }
    }
    float ni = rsqrtf(fmaxf((float)cnt, 1.0f));
    aggb[((size_t)n << 6) + lane] = f2bf2(ax * ni, ay * ni);
}

// Fused QKV projection via bf16 MFMA. grid (391, 3):
// y=0 -> qb (bf16 rows), y=1 -> kf (fp8 rows), y=2 -> vb (bf16 rows).
__global__ __launch_bounds__(256) void k_qkv(
    const uint* __restrict__ aggb, const uint* __restrict__ wt,
    const float* __restrict__ bQ, const float* __restrict__ bK,
    const float* __restrict__ bV,
    uint* __restrict__ qb, uint* __restrict__ kf, uint* __restrict__ vb)
{
    const int y = blockIdx.y;
    const int row0 = blockIdx.x * 128;
    const float* bias = (y == 0) ? bQ : (y == 1) ? bK : bV;

    __shared__ uint sA[128 * 68];   // A tile, row stride 68 uints

    const int t = threadIdx.x;
    for (int idx = t; idx < 128 * 16; idx += 256) {
        int r = idx >> 4, c4 = (idx & 15) << 2;
        int row = row0 + r;
        uint4 v = make_uint4(0u, 0u, 0u, 0u);
        if (row < N_NODES) v = *(const uint4*)(aggb + ((size_t)row << 6) + c4);
        *(uint4*)(&sA[r * 68 + c4]) = v;
    }
    __syncthreads();

    const int wave = t >> 6;
    const int lane = t & 63;
    const int mrow = lane & 15;     // m (A) / n (B) / col (C)
    const int kq   = lane >> 4;     // 0..3
    const int mbase = wave * 32;
    const uint* wty = wt + (y << 13);

    floatx4 acc[2][8];
    for (int a = 0; a < 2; ++a)
        for (int b = 0; b < 8; ++b)
            acc[a][b] = (floatx4){0.f, 0.f, 0.f, 0.f};

    for (int kc = 0; kc < 128; kc += 32) {
        int koff = (kc >> 1) + (kq << 2);    // uint offset within a row
        short8 afr[2], bfr[8];
        for (int mt = 0; mt < 2; ++mt) {
            U16 u; u.u = *(const uint4*)(&sA[(mbase + mt * 16 + mrow) * 68 + koff]);
            afr[mt] = u.s;
        }
        for (int nt = 0; nt < 8; ++nt) {
            U16 u; u.u = *(const uint4*)(wty + ((nt * 16 + mrow) << 6) + koff);
            bfr[nt] = u.s;
        }
        for (int mt = 0; mt < 2; ++mt)
            for (int nt = 0; nt < 8; ++nt)
                acc[mt][nt] = __builtin_amdgcn_mfma_f32_16x16x32_bf16(
                    afr[mt], bfr[nt], acc[mt][nt], 0, 0, 0);
    }

    // C/D: col = lane&15 (= mrow), row = kq*4 + reg.
    if (y == 1) {
        // K -> fp8: gather 4 consecutive cols (lanes lane^1, lane^2, lane^3)
        for (int mt = 0; mt < 2; ++mt) {
            int rbase = row0 + mbase + mt * 16 + kq * 4;
            for (int nt = 0; nt < 8; ++nt) {
                int c = nt * 16 + mrow;
                float bv = bias[c];
                for (int r = 0; r < 4; ++r) {
                    float v = fmaxf(acc[mt][nt][r] + bv, 0.f);
                    uint b0 = f2e4m3(v);
                    uint b1 = __shfl_xor((int)b0, 1);
                    uint b2 = __shfl_xor((int)b0, 2);
                    uint b3 = __shfl_xor((int)b0, 3);
                    int row = rbase + r;
                    if (((lane & 3) == 0) && row < N_NODES)
                        kf[((size_t)row << 5) + (c >> 2)] =
                            b0 | (b1 << 8) | (b2 << 16) | (b3 << 24);
                }
            }
        }
    } else {
        uint* obuf = (y == 0) ? qb : vb;
        for (int mt = 0; mt < 2; ++mt) {
            int rbase = row0 + mbase + mt * 16 + kq * 4;
            for (int nt = 0; nt < 8; ++nt) {
                int c = nt * 16 + mrow;
                float bv = bias[c];
                for (int r = 0; r < 4; ++r) {
                    float v = fmaxf(acc[mt][nt][r] + bv, 0.f);
                    float pv = __shfl_xor(v, 1);
                    int row = rbase + r;
                    if (((lane & 1) == 0) && row < N_NODES)
                        obuf[((size_t)row << 6) + (c >> 1)] = f2bf2(v, pv);
                }
            }
        }
    }
}

__device__ __forceinline__ void attn_step(ushort kw, uint vu, float qx, float qy,
                                          float& ax, float& ay, float& zacc) {
    float p = e4m3f(kw & 0xFFu) * qx + e4m3f(kw >> 8) * qy;
    p += __shfl_xor(p, 1);
    p += __shfl_xor(p, 2);
    p += __shfl_xor(p, 4);
    float sc = __expf(fminf(fmaxf(p * 0.25f, -10.f), 10.f));
    ax += bflo(vu) * sc;
    ay += bfhi(vu) * sc;
    zacc += sc;
}

// Attention gather: fp8 K rows (128 B) + bf16 V rows (256 B); unroll x8.
// lane owns dim pair `lane` (head = lane>>3).
__global__ __launch_bounds__(256) void k_attn(
    const int* __restrict__ cnt_in, const int* __restrict__ bucket,
    const int* __restrict__ ovf_n, const int2* __restrict__ ovf,
    const uint* __restrict__ qb, const uint* __restrict__ kf,
    const uint* __restrict__ vb, float* __restrict__ out)
{
    int n = blockIdx.x * 4 + (threadIdx.x >> 6);
    int lane = threadIdx.x & 63;
    int cnt = cnt_in[n];
    int m = min(cnt, CAP);
    const int* b = bucket + ((size_t)n << 6);
    const ushort* kfp = (const ushort*)kf;

    uint qu = qb[((size_t)n << 6) + lane];
    float qx = bflo(qu), qy = bfhi(qu);
    float ax = 0.f, ay = 0.f, zacc = 0.f;

    int i = 0;
    for (; i + 8 <= m; i += 8) {
        int s[8]; ushort kw[8]; uint vu[8];
        #pragma unroll
        for (int j = 0; j < 8; ++j) s[j] = b[i + j];
        #pragma unroll
        for (int j = 0; j < 8; ++j) {
            kw[j] = kfp[((size_t)s[j] << 6) + lane];
            vu[j] = vb[((size_t)s[j] << 6) + lane];
        }
        #pragma unroll
        for (int j = 0; j < 8; ++j)
            attn_step(kw[j], vu[j], qx, qy, ax, ay, zacc);
    }
    for (; i < m; ++i) {
        int s = b[i];
        attn_step(kfp[((size_t)s << 6) + lane], vb[((size_t)s << 6) + lane],
                  qx, qy, ax, ay, zacc);
    }
    if (cnt > CAP) {                       // statistically never; correctness net
        int on = min(*ovf_n, OVF_CAP);
        for (int j = 0; j < on; ++j) {
            int2 pr = ovf[j];
            if (pr.x == n)
                attn_step(kfp[((size_t)pr.y << 6) + lane],
                          vb[((size_t)pr.y << 6) + lane],
                          qx, qy, ax, ay, zacc);
        }
    }

    float inv = 1.0f / (zacc + 1e-6f);
    float2 o; o.x = ax * inv; o.y = ay * inv;
    *(float2*)(out + ((size_t)n << 7) + (lane << 1)) = o;
}

extern "C" void kernel_launch(void* const* d_in, const int* in_sizes, int n_in,
                              void* d_out, int out_size, void* d_ws, size_t ws_size,
                              hipStream_t stream) {
    const float* h   = (const float*)d_in[0];
    const float* WQ  = (const float*)d_in[1];
    const float* bQ  = (const float*)d_in[2];
    const float* WK  = (const float*)d_in[3];
    const float* bK  = (const float*)d_in[4];
    const float* WV  = (const float*)d_in[5];
    const float* bV  = (const float*)d_in[6];
    const int*   src = (const int*)d_in[7];
    const int*   dst = (const int*)d_in[8];
    float* out = (float*)d_out;
    float* ws  = (float*)d_ws;
    int*   wsi = (int*)d_ws;

    int*   cnt_out = wsi + O_CNTO;
    int*   cnt_in  = wsi + O_CNTI;
    int*   ovf_n   = wsi + O_OVFN;
    int2*  ovf     = (int2*)(wsi + O_OVF);
    int*   bucket  = wsi + O_BUCKET;
    uint*  hb      = (uint*)(ws + O_HB);
    uint*  aggb    = (uint*)(ws + O_AGGB);
    uint*  wt      = (uint*)(ws + O_WT);
    uint*  qb      = (uint*)(ws + O_QB);
    uint*  kf      = (uint*)(ws + O_KF);
    uint*  vb      = (uint*)(ws + O_VB);

    hipMemsetAsync(wsi, 0, (2 * N_NODES + 2) * sizeof(int), stream);

    k_build<<<N_EDGES / 256, 256, 0, stream>>>(src, dst, cnt_out, cnt_in,
                                               bucket, ovf_n, ovf);
    k_hbwt<<<96 + (N_NODES * 64) / 256, 256, 0, stream>>>(h, cnt_out, hb,
                                                          WQ, WK, WV, wt);

    k_agg<<<N_NODES / 4, 256, 0, stream>>>(cnt_in, bucket, ovf_n, ovf, hb, aggb);

    dim3 g_qkv((N_NODES + 127) / 128, 3);
    k_qkv<<<g_qkv, 256, 0, stream>>>(aggb, wt, bQ, bK, bV, qb, kf, vb);

    k_attn<<<N_NODES / 4, 256, 0, stream>>>(cnt_in, bucket, ovf_n, ovf,
                                            qb, kf, vb, out);
}